// Round 1
// 851.825 us; speedup vs baseline: 1.1963x; 1.1963x over previous
//
#include <hip/hip_runtime.h>
#include <stdint.h>
#include <type_traits>

#define TOKENS  4096
#define D_MODEL 4096
#define D_FF    16384
#define K_SEL   4096

typedef __attribute__((ext_vector_type(8))) short short8;
typedef __attribute__((ext_vector_type(4))) float float4v;

typedef const __attribute__((address_space(1))) unsigned int* gptr_t;
typedef __attribute__((address_space(3))) unsigned int* lptr_t;

// fp32 -> bf16 round-to-nearest-even
__device__ inline unsigned short f2bf(float f) {
    union { float f; unsigned int u; } v; v.f = f;
    unsigned int r = v.u + 0x7fffu + ((v.u >> 16) & 1u);
    return (unsigned short)(r >> 16);
}

// ---------------------------------------------------------------------------
// Prep kernel 1: cast (and optionally row-gather) fp32 [rows][cols] -> bf16.
// ---------------------------------------------------------------------------
__global__ void gather_cast_kernel(const float* __restrict__ src,
                                   const int* __restrict__ idx,
                                   unsigned short* __restrict__ dst,
                                   int cols) {
    long e = ((long)blockIdx.x * blockDim.x + threadIdx.x) * 8;
    int row = (int)(e / cols);
    int col = (int)(e - (long)row * cols);
    long srow = idx ? (long)idx[row] : (long)row;
    const float4* s = (const float4*)(src + srow * cols + col);
    float4 a = s[0], b = s[1];
    short8 o;
    o[0] = (short)f2bf(a.x); o[1] = (short)f2bf(a.y);
    o[2] = (short)f2bf(a.z); o[3] = (short)f2bf(a.w);
    o[4] = (short)f2bf(b.x); o[5] = (short)f2bf(b.y);
    o[6] = (short)f2bf(b.z); o[7] = (short)f2bf(b.w);
    *(short8*)(dst + e) = o;
}

// ---------------------------------------------------------------------------
// Prep kernel 2: gathered transpose-cast. dst[n][k] = bf16(src[idx[k]][n]).
// ---------------------------------------------------------------------------
__global__ void gather_transpose_cast_kernel(const float* __restrict__ src,
                                             const int* __restrict__ idx,
                                             unsigned short* __restrict__ dst,
                                             int srcCols, int rows) {
    __shared__ float tile[32][33];
    int tx = threadIdx.x;   // 0..31
    int ty = threadIdx.y;   // 0..7
    int k0 = blockIdx.x * 32;
    int n0 = blockIdx.y * 32;
#pragma unroll
    for (int r = 0; r < 4; ++r) {
        int k = k0 + ty + r * 8;
        long sr = idx[k];
        tile[ty + r * 8][tx] = src[sr * srcCols + n0 + tx];
    }
    __syncthreads();
#pragma unroll
    for (int r = 0; r < 4; ++r) {
        int n = n0 + ty + r * 8;
        dst[(long)n * rows + k0 + tx] = f2bf(tile[tx][ty + r * 8]);
    }
}

// ---------------------------------------------------------------------------
// NT bf16 GEMM, 256x256 tile, 512 threads = 8 waves (2M x 4N), per-wave
// output 128x64, acc[8][4]. K pipelined in 32-wide sub-tiles through a ring
// of 4 LDS slots (A 16KB + B 16KB per slot = 128 KB total, 1 block/CU).
//
// Pipeline invariant (counted vmcnt, never drains in steady state):
//   at top of iter s: slots s+1, s+2 in flight (8 loads/wave), vmcnt(8)
//   guarantees slot s complete; stage(s+3) overwrites slot (s-1)&3 whose
//   reads finished before this iteration's barrier.
//
// LDS layout per slot: chunk-major [q][m][8 bf16] (q = k-octet 0..3,
// m = row 0..255): global_load_lds-compatible (wave base + lane*16) and
// fragment ds_read_b128 is conflict-free (measured 0 conflicts at 128 tile).
//
// MODE 0: fp32 out, bias[col].  MODE 1: bf16 out, relu, bias[bidx[col]].
// ---------------------------------------------------------------------------
template <int MODE>
__global__ __launch_bounds__(512)
void gemm_nt256(const unsigned short* __restrict__ A,
                const unsigned short* __restrict__ B,
                const float* __restrict__ bias,
                const int* __restrict__ bidx,
                void* __restrict__ Cout,
                int M, int N, int K) {
    extern __shared__ unsigned short lds[];      // 131072 B
    unsigned short* AsB = lds;                   // 4 slots x 8192 shorts
    unsigned short* BsB = lds + 32768;           // 4 slots x 8192 shorts

    const int tid  = threadIdx.x;
    const int lane = tid & 63;
    const int wave = tid >> 6;      // 0..7
    const int wm   = wave >> 2;     // 0..1
    const int wn   = wave & 3;      // 0..3
    const int quad = lane >> 4;     // 0..3
    const int lr   = lane & 15;     // 0..15

    // Bijective XCD swizzle (nwg = 256, divisible by 8).
    const int nwg  = (int)(gridDim.x * gridDim.y);
    const int orig = (int)(blockIdx.y * gridDim.x + blockIdx.x);
    const int swz  = (orig & 7) * (nwg >> 3) + (orig >> 3);
    const int bx   = swz % (int)gridDim.x;
    const int by   = swz / (int)gridDim.x;
    const int bm   = by * 256;
    const int bn   = bx * 256;

    // Staging descriptors: 2 A-chunks + 2 B-chunks per thread per sub-tile.
    // Chunk p = i*512 + tid: q = p>>8 (k-octet), m = p&255 (row). 16 B each.
    const unsigned short* aSrc[2];
    const unsigned short* bSrc[2];
    int ldsOff[2];
#pragma unroll
    for (int i = 0; i < 2; ++i) {
        int p = i * 512 + tid;
        int q = p >> 8, m = p & 255;
        aSrc[i] = A + (long)(bm + m) * K + q * 8;
        bSrc[i] = B + (long)(bn + m) * K + q * 8;
        ldsOff[i] = p * 8;
    }

    float4v acc[8][4];
#pragma unroll
    for (int i = 0; i < 8; ++i)
#pragma unroll
        for (int j = 0; j < 4; ++j)
            acc[i][j] = (float4v)(0.f);

    const int NSUB = K >> 5;   // 128 sub-tiles of K=32

    auto stageA = [&](int s) {
        unsigned short* dst = AsB + (s & 3) * 8192;
#pragma unroll
        for (int i = 0; i < 2; ++i)
            __builtin_amdgcn_global_load_lds((gptr_t)(aSrc[i] + s * 32),
                                             (lptr_t)(dst + ldsOff[i]), 16, 0, 0);
    };
    auto stageB = [&](int s) {
        unsigned short* dst = BsB + (s & 3) * 8192;
#pragma unroll
        for (int i = 0; i < 2; ++i)
            __builtin_amdgcn_global_load_lds((gptr_t)(bSrc[i] + s * 32),
                                             (lptr_t)(dst + ldsOff[i]), 16, 0, 0);
    };

    // Prologue: fill 3 slots ahead (12 loads/wave in flight).
    stageA(0); stageB(0); stageA(1); stageB(1); stageA(2); stageB(2);

    const int rowA = wm * 128 + lr;   // A fragment row base for this wave
    const int rowB = wn * 64 + lr;    // B fragment row base for this wave

    auto kiter = [&](int s, auto waitc, auto dostage) {
        constexpr int  W  = decltype(waitc)::value;
        constexpr bool DS = decltype(dostage)::value;
        // wait for slot s (leave W loads in flight), then raw barrier so all
        // waves' contributions to slot s are visible. NO vmcnt(0) drain here.
        if constexpr (W == 8)
            asm volatile("s_waitcnt vmcnt(8)\n\ts_barrier" ::: "memory");
        else if constexpr (W == 4)
            asm volatile("s_waitcnt vmcnt(4)\n\ts_barrier" ::: "memory");
        else
            asm volatile("s_waitcnt vmcnt(0)\n\ts_barrier" ::: "memory");

        const unsigned short* sA = AsB + (s & 3) * 8192;
        const unsigned short* sB = BsB + (s & 3) * 8192;
        const unsigned short* pA = sA + (quad * 256 + rowA) * 8;
        const unsigned short* pB = sB + (quad * 256 + rowB) * 8;

        short8 af[8], bfr[4];
        // phase 1: A rows 0..63 of wave tile + all B cols
#pragma unroll
        for (int i = 0; i < 4; ++i) af[i] = *(const short8*)(pA + i * 128);
#pragma unroll
        for (int j = 0; j < 4; ++j) bfr[j] = *(const short8*)(pB + j * 128);
        if constexpr (DS) stageA(s + 3);   // issue next-tile A loads early
        __builtin_amdgcn_s_setprio(1);
#pragma unroll
        for (int i = 0; i < 4; ++i)
#pragma unroll
            for (int j = 0; j < 4; ++j)
                acc[i][j] = __builtin_amdgcn_mfma_f32_16x16x32_bf16(
                    af[i], bfr[j], acc[i][j], 0, 0, 0);
        __builtin_amdgcn_s_setprio(0);

        // phase 2: A rows 64..127 of wave tile
#pragma unroll
        for (int i = 0; i < 4; ++i) af[4 + i] = *(const short8*)(pA + 512 + i * 128);
        if constexpr (DS) stageB(s + 3);   // issue next-tile B loads
        __builtin_amdgcn_s_setprio(1);
#pragma unroll
        for (int i = 4; i < 8; ++i)
#pragma unroll
            for (int j = 0; j < 4; ++j)
                acc[i][j] = __builtin_amdgcn_mfma_f32_16x16x32_bf16(
                    af[i], bfr[j], acc[i][j], 0, 0, 0);
        __builtin_amdgcn_s_setprio(0);
    };

    for (int s = 0; s < NSUB - 3; ++s)
        kiter(s, std::integral_constant<int, 8>{}, std::true_type{});
    kiter(NSUB - 3, std::integral_constant<int, 8>{}, std::false_type{});
    kiter(NSUB - 2, std::integral_constant<int, 4>{}, std::false_type{});
    kiter(NSUB - 1, std::integral_constant<int, 0>{}, std::false_type{});

    // Epilogue: verified C/D mapping col = lr, row = quad*4 + r.
#pragma unroll
    for (int i = 0; i < 8; ++i) {
        int rowBase = bm + wm * 128 + i * 16 + quad * 4;
#pragma unroll
        for (int j = 0; j < 4; ++j) {
            int col = bn + wn * 64 + j * 16 + lr;
            float bv = (MODE == 1) ? bias[bidx[col]] : bias[col];
#pragma unroll
            for (int r = 0; r < 4; ++r) {
                float v = acc[i][j][r] + bv;
                long off = (long)(rowBase + r) * N + col;
                if (MODE == 1) {
                    v = v > 0.f ? v : 0.f;
                    ((unsigned short*)Cout)[off] = f2bf(v);
                } else {
                    ((float*)Cout)[off] = v;
                }
            }
        }
    }
}

extern "C" void kernel_launch(void* const* d_in, const int* in_sizes, int n_in,
                              void* d_out, int out_size, void* d_ws, size_t ws_size,
                              hipStream_t stream) {
    const float* x      = (const float*)d_in[0];
    const float* fc1_w  = (const float*)d_in[1];
    const float* bias1  = (const float*)d_in[2];
    const float* fc2_wt = (const float*)d_in[3];
    const float* bias2  = (const float*)d_in[4];
    const int*   idx    = (const int*)d_in[5];

    static bool inited = false;
    if (!inited) {
        hipFuncSetAttribute(reinterpret_cast<const void*>(&gemm_nt256<1>),
                            hipFuncAttributeMaxDynamicSharedMemorySize, 131072);
        hipFuncSetAttribute(reinterpret_cast<const void*>(&gemm_nt256<0>),
                            hipFuncAttributeMaxDynamicSharedMemorySize, 131072);
        inited = true;
    }

    char* ws = (char*)d_ws;
    unsigned short* Xb   = (unsigned short*)(ws);                         // 32 MB
    unsigned short* W1g  = (unsigned short*)(ws + ((size_t)32 << 20));    // 32 MB
    unsigned short* W2gT = (unsigned short*)(ws + ((size_t)64 << 20));    // 32 MB
    unsigned short* H    = (unsigned short*)(ws + ((size_t)96 << 20));    // 32 MB

    // 1) cast x -> bf16
    gather_cast_kernel<<<(TOKENS * D_MODEL / 8) / 256, 256, 0, stream>>>(
        x, nullptr, Xb, D_MODEL);
    // 2) gather fc1 rows -> bf16 W1g[k][d]
    gather_cast_kernel<<<(K_SEL * D_MODEL / 8) / 256, 256, 0, stream>>>(
        fc1_w, idx, W1g, D_MODEL);
    // 3) gather + transpose fc2 rows -> bf16 W2gT[n][k]
    gather_transpose_cast_kernel<<<dim3(K_SEL / 32, D_MODEL / 32), dim3(32, 8), 0, stream>>>(
        fc2_wt, idx, W2gT, D_MODEL, K_SEL);
    // 4) H = relu(Xb * W1g^T + bias1[idx])   [TOKENS x K_SEL] bf16
    gemm_nt256<1><<<dim3(K_SEL / 256, TOKENS / 256), 512, 131072, stream>>>(
        Xb, W1g, bias1, idx, (void*)H, TOKENS, K_SEL, D_MODEL);
    // 5) out = H * W2gT^T + bias2            [TOKENS x D_MODEL] fp32
    gemm_nt256<0><<<dim3(D_MODEL / 256, TOKENS / 256), 512, 131072, stream>>>(
        H, W2gT, bias2, nullptr, d_out, TOKENS, D_MODEL, K_SEL);
}

// Round 2
// 824.043 us; speedup vs baseline: 1.2367x; 1.0337x over previous
//
#include <hip/hip_runtime.h>
#include <stdint.h>
#include <type_traits>

#define TOKENS  4096
#define D_MODEL 4096
#define D_FF    16384
#define K_SEL   4096

typedef __attribute__((ext_vector_type(8))) short short8;
typedef __attribute__((ext_vector_type(4))) float float4v;

typedef const __attribute__((address_space(1))) unsigned int* gptr_t;
typedef __attribute__((address_space(3))) unsigned int* lptr_t;

// fp32 -> bf16 round-to-nearest-even
__device__ inline unsigned short f2bf(float f) {
    union { float f; unsigned int u; } v; v.f = f;
    unsigned int r = v.u + 0x7fffu + ((v.u >> 16) & 1u);
    return (unsigned short)(r >> 16);
}

// ---------------------------------------------------------------------------
// Prep kernel 1: cast (and optionally row-gather) fp32 [rows][cols] -> bf16.
// ---------------------------------------------------------------------------
__global__ void gather_cast_kernel(const float* __restrict__ src,
                                   const int* __restrict__ idx,
                                   unsigned short* __restrict__ dst,
                                   int cols) {
    long e = ((long)blockIdx.x * blockDim.x + threadIdx.x) * 8;
    int row = (int)(e / cols);
    int col = (int)(e - (long)row * cols);
    long srow = idx ? (long)idx[row] : (long)row;
    const float4* s = (const float4*)(src + srow * cols + col);
    float4 a = s[0], b = s[1];
    short8 o;
    o[0] = (short)f2bf(a.x); o[1] = (short)f2bf(a.y);
    o[2] = (short)f2bf(a.z); o[3] = (short)f2bf(a.w);
    o[4] = (short)f2bf(b.x); o[5] = (short)f2bf(b.y);
    o[6] = (short)f2bf(b.z); o[7] = (short)f2bf(b.w);
    *(short8*)(dst + e) = o;
}

// ---------------------------------------------------------------------------
// Prep kernel 2: gathered transpose-cast, 64x64 tiles.
// dst[n][k] = bf16(src[idx[k]][n]).  float4 loads, short8 (16B) stores.
// LDS [64][65] fp32: store-side column reads are 2-way bank aliased (free).
// ---------------------------------------------------------------------------
__global__ void gather_transpose_cast64(const float* __restrict__ src,
                                        const int* __restrict__ idx,
                                        unsigned short* __restrict__ dst,
                                        int srcCols, int rows) {
    __shared__ float tile[64][65];
    int t = threadIdx.x;            // 0..255
    int k0 = blockIdx.x * 64;
    int n0 = blockIdx.y * 64;
    int fr = t >> 4;                // 0..15
    int fc = (t & 15) * 4;          // 0,4,..,60
#pragma unroll
    for (int p = 0; p < 4; ++p) {
        int k = fr + p * 16;
        long sr = idx[k0 + k];
        float4 v = *(const float4*)(src + sr * srcCols + n0 + fc);
        tile[k][fc] = v.x; tile[k][fc + 1] = v.y;
        tile[k][fc + 2] = v.z; tile[k][fc + 3] = v.w;
    }
    __syncthreads();
#pragma unroll
    for (int p = 0; p < 2; ++p) {
        int n  = (t >> 3) + p * 32;  // 0..63
        int kc = (t & 7) * 8;        // 0,8,..,56
        short8 o;
#pragma unroll
        for (int j = 0; j < 8; ++j)
            o[j] = (short)f2bf(tile[kc + j][n]);
        *(short8*)(dst + (long)(n0 + n) * rows + k0 + kc) = o;
    }
}

// ---------------------------------------------------------------------------
// NT bf16 GEMM, 256x256 tile, 512 threads = 8 waves (2M x 4N), per-wave
// output 128x64, acc[8][4]. K pipelined in 32-wide sub-tiles through a ring
// of 4 LDS slots (A 16KB + B 16KB per slot = 128 KB, 1 block/CU).
//
// 2 phases per sub-tile, m201-style double-barrier sandwich per phase:
//   {ds_read frags; issue stage; sched_barrier; s_barrier; lgkmcnt(0);
//    sched_barrier; setprio(1); 16 MFMA; setprio(0); trailing s_barrier}
// ds_read latency hides under the barrier wait; all waves MFMA in aligned
// bursts (620 cyc/CU burst vs ~200 cyc read burst -> ~60% MfmaUtil ceiling).
//
// Counted vmcnt (never drains in steady state): trailing sync of sub-tile s
// is {vmcnt(8); s_barrier} -> slot s+1 complete for all waves, slots s+2,s+3
// still in flight. stage(s+3) overwrites slot (s-1)&3, whose reads were
// lgkmcnt-drained before every wave's last MFMA cluster of sub-tile s-1,
// hence complete before the barrier that precedes the stage issue.
//
// MODE 0: fp32 out, bias[col].  MODE 1: bf16 out, relu, bias[bidx[col]].
// ---------------------------------------------------------------------------
template <int MODE>
__global__ __launch_bounds__(512)
void gemm_nt256(const unsigned short* __restrict__ A,
                const unsigned short* __restrict__ B,
                const float* __restrict__ bias,
                const int* __restrict__ bidx,
                void* __restrict__ Cout,
                int M, int N, int K) {
    extern __shared__ unsigned short lds[];      // 131072 B
    unsigned short* AsB = lds;                   // 4 slots x 8192 shorts
    unsigned short* BsB = lds + 32768;           // 4 slots x 8192 shorts

    const int tid  = threadIdx.x;
    const int lane = tid & 63;
    const int wave = tid >> 6;      // 0..7
    const int wm   = wave >> 2;     // 0..1
    const int wn   = wave & 3;      // 0..3
    const int quad = lane >> 4;     // 0..3
    const int lr   = lane & 15;     // 0..15

    // Bijective XCD swizzle (nwg = 256, divisible by 8).
    const int nwg  = (int)(gridDim.x * gridDim.y);
    const int orig = (int)(blockIdx.y * gridDim.x + blockIdx.x);
    const int swz  = (orig & 7) * (nwg >> 3) + (orig >> 3);
    const int bx   = swz % (int)gridDim.x;
    const int by   = swz / (int)gridDim.x;
    const int bm   = by * 256;
    const int bn   = bx * 256;

    // Staging descriptors: 2 A-chunks + 2 B-chunks per thread per sub-tile.
    const unsigned short* aSrc[2];
    const unsigned short* bSrc[2];
    int ldsOff[2];
#pragma unroll
    for (int i = 0; i < 2; ++i) {
        int p = i * 512 + tid;
        int q = p >> 8, m = p & 255;
        aSrc[i] = A + (long)(bm + m) * K + q * 8;
        bSrc[i] = B + (long)(bn + m) * K + q * 8;
        ldsOff[i] = p * 8;
    }

    float4v acc[8][4];
#pragma unroll
    for (int i = 0; i < 8; ++i)
#pragma unroll
        for (int j = 0; j < 4; ++j)
            acc[i][j] = (float4v)(0.f);

    const int NSUB = K >> 5;   // sub-tiles of K=32

    auto stageA = [&](int s) {
        unsigned short* dst = AsB + (s & 3) * 8192;
#pragma unroll
        for (int i = 0; i < 2; ++i)
            __builtin_amdgcn_global_load_lds((gptr_t)(aSrc[i] + s * 32),
                                             (lptr_t)(dst + ldsOff[i]), 16, 0, 0);
    };
    auto stageB = [&](int s) {
        unsigned short* dst = BsB + (s & 3) * 8192;
#pragma unroll
        for (int i = 0; i < 2; ++i)
            __builtin_amdgcn_global_load_lds((gptr_t)(bSrc[i] + s * 32),
                                             (lptr_t)(dst + ldsOff[i]), 16, 0, 0);
    };

    // Prologue: fill 3 slots ahead, then establish slot-0-ready invariant.
    stageA(0); stageB(0); stageA(1); stageB(1); stageA(2); stageB(2);
    asm volatile("s_waitcnt vmcnt(8)" ::: "memory");
    __builtin_amdgcn_s_barrier();

    const int rowA = wm * 128 + lr;
    const int rowB = wn * 64 + lr;

    auto kiter = [&](int s, auto wtrail, auto dostage) {
        constexpr int  W  = decltype(wtrail)::value;
        constexpr bool DS = decltype(dostage)::value;

        const unsigned short* sA = AsB + (s & 3) * 8192;
        const unsigned short* sB = BsB + (s & 3) * 8192;
        const unsigned short* pA = sA + (quad * 256 + rowA) * 8;
        const unsigned short* pB = sB + (quad * 256 + rowB) * 8;

        short8 af[8], bfr[4];

        // ---- phase 0: reads issued BEFORE barrier, MFMA burst after ----
#pragma unroll
        for (int i = 0; i < 4; ++i) af[i] = *(const short8*)(pA + i * 128);
#pragma unroll
        for (int j = 0; j < 4; ++j) bfr[j] = *(const short8*)(pB + j * 128);
        if constexpr (DS) stageA(s + 3);
        __builtin_amdgcn_sched_barrier(0);        // pin reads before barrier
        __builtin_amdgcn_s_barrier();
        asm volatile("s_waitcnt lgkmcnt(0)" ::: "memory");
        __builtin_amdgcn_sched_barrier(0);        // pin MFMAs after the wait
        __builtin_amdgcn_s_setprio(1);
#pragma unroll
        for (int i = 0; i < 4; ++i)
#pragma unroll
            for (int j = 0; j < 4; ++j)
                acc[i][j] = __builtin_amdgcn_mfma_f32_16x16x32_bf16(
                    af[i], bfr[j], acc[i][j], 0, 0, 0);
        __builtin_amdgcn_s_setprio(0);
        __builtin_amdgcn_sched_barrier(0);
        __builtin_amdgcn_s_barrier();             // trailing barrier ph0

        // ---- phase 1 ----
#pragma unroll
        for (int i = 0; i < 4; ++i) af[4 + i] = *(const short8*)(pA + 512 + i * 128);
        if constexpr (DS) stageB(s + 3);
        __builtin_amdgcn_sched_barrier(0);
        __builtin_amdgcn_s_barrier();
        asm volatile("s_waitcnt lgkmcnt(0)" ::: "memory");
        __builtin_amdgcn_sched_barrier(0);
        __builtin_amdgcn_s_setprio(1);
#pragma unroll
        for (int i = 4; i < 8; ++i)
#pragma unroll
            for (int j = 0; j < 4; ++j)
                acc[i][j] = __builtin_amdgcn_mfma_f32_16x16x32_bf16(
                    af[i], bfr[j], acc[i][j], 0, 0, 0);
        __builtin_amdgcn_s_setprio(0);
        __builtin_amdgcn_sched_barrier(0);
        // trailing sync of sub-tile: make slot s+1 ready for all waves,
        // leaving later slots' loads in flight (counted, never drains).
        if constexpr (W == 8)
            asm volatile("s_waitcnt vmcnt(8)" ::: "memory");
        else if constexpr (W == 4)
            asm volatile("s_waitcnt vmcnt(4)" ::: "memory");
        else
            asm volatile("s_waitcnt vmcnt(0)" ::: "memory");
        __builtin_amdgcn_s_barrier();
    };

    for (int s = 0; s < NSUB - 3; ++s)
        kiter(s, std::integral_constant<int, 8>{}, std::true_type{});
    kiter(NSUB - 3, std::integral_constant<int, 4>{}, std::false_type{});
    kiter(NSUB - 2, std::integral_constant<int, 0>{}, std::false_type{});
    kiter(NSUB - 1, std::integral_constant<int, 0>{}, std::false_type{});

    // Epilogue: C/D mapping col = lr, row = quad*4 + r.
#pragma unroll
    for (int i = 0; i < 8; ++i) {
        int rowBase = bm + wm * 128 + i * 16 + quad * 4;
#pragma unroll
        for (int j = 0; j < 4; ++j) {
            int col = bn + wn * 64 + j * 16 + lr;
            float bv = (MODE == 1) ? bias[bidx[col]] : bias[col];
#pragma unroll
            for (int r = 0; r < 4; ++r) {
                float v = acc[i][j][r] + bv;
                long off = (long)(rowBase + r) * N + col;
                if (MODE == 1) {
                    v = v > 0.f ? v : 0.f;
                    ((unsigned short*)Cout)[off] = f2bf(v);
                } else {
                    ((float*)Cout)[off] = v;
                }
            }
        }
    }
}

extern "C" void kernel_launch(void* const* d_in, const int* in_sizes, int n_in,
                              void* d_out, int out_size, void* d_ws, size_t ws_size,
                              hipStream_t stream) {
    const float* x      = (const float*)d_in[0];
    const float* fc1_w  = (const float*)d_in[1];
    const float* bias1  = (const float*)d_in[2];
    const float* fc2_wt = (const float*)d_in[3];
    const float* bias2  = (const float*)d_in[4];
    const int*   idx    = (const int*)d_in[5];

    static bool inited = false;
    if (!inited) {
        hipFuncSetAttribute(reinterpret_cast<const void*>(&gemm_nt256<1>),
                            hipFuncAttributeMaxDynamicSharedMemorySize, 131072);
        hipFuncSetAttribute(reinterpret_cast<const void*>(&gemm_nt256<0>),
                            hipFuncAttributeMaxDynamicSharedMemorySize, 131072);
        inited = true;
    }

    char* ws = (char*)d_ws;
    unsigned short* Xb   = (unsigned short*)(ws);                         // 32 MB
    unsigned short* W1g  = (unsigned short*)(ws + ((size_t)32 << 20));    // 32 MB
    unsigned short* W2gT = (unsigned short*)(ws + ((size_t)64 << 20));    // 32 MB
    unsigned short* H    = (unsigned short*)(ws + ((size_t)96 << 20));    // 32 MB

    // 1) cast x -> bf16
    gather_cast_kernel<<<(TOKENS * D_MODEL / 8) / 256, 256, 0, stream>>>(
        x, nullptr, Xb, D_MODEL);
    // 2) gather fc1 rows -> bf16 W1g[k][d]
    gather_cast_kernel<<<(K_SEL * D_MODEL / 8) / 256, 256, 0, stream>>>(
        fc1_w, idx, W1g, D_MODEL);
    // 3) gather + transpose fc2 rows -> bf16 W2gT[n][k]
    gather_transpose_cast64<<<dim3(K_SEL / 64, D_MODEL / 64), 256, 0, stream>>>(
        fc2_wt, idx, W2gT, D_MODEL, K_SEL);
    // 4) H = relu(Xb * W1g^T + bias1[idx])   [TOKENS x K_SEL] bf16
    gemm_nt256<1><<<dim3(K_SEL / 256, TOKENS / 256), 512, 131072, stream>>>(
        Xb, W1g, bias1, idx, (void*)H, TOKENS, K_SEL, D_MODEL);
    // 5) out = H * W2gT^T + bias2            [TOKENS x D_MODEL] fp32
    gemm_nt256<0><<<dim3(D_MODEL / 256, TOKENS / 256), 512, 131072, stream>>>(
        H, W2gT, bias2, nullptr, d_out, TOKENS, D_MODEL, K_SEL);
}